// Round 3
// baseline (3659.319 us; speedup 1.0000x reference)
//
#include <hip/hip_runtime.h>
#include <hip/hip_fp16.h>
#include <hip/hip_cooperative_groups.h>
#include <math.h>

namespace cg = cooperative_groups;

#define HW_ (512 * 512)

__device__ inline float2 cadd(float2 a, float2 b){ return make_float2(a.x+b.x, a.y+b.y); }
__device__ inline float2 csub(float2 a, float2 b){ return make_float2(a.x-b.x, a.y-b.y); }
__device__ inline float2 cmulf(float2 a, float2 b){ return make_float2(a.x*b.x-a.y*b.y, a.x*b.y+a.y*b.x); }
__device__ inline float bf2f(unsigned short u){ return __uint_as_float(((unsigned int)u) << 16); }
__device__ inline unsigned short f2bf(float f){
    unsigned int x = __float_as_uint(f);
    x += 0x7fffu + ((x >> 16) & 1u);
    return (unsigned short)(x >> 16);
}
__device__ inline unsigned int pack_h2(float2 v){
    __half2 h = __floats2half2_rn(v.x, v.y);
    return *(unsigned int*)&h;
}
__device__ inline float2 unpack_h2(unsigned int u){
    __half2 h = *(__half2*)&u;
    return make_float2(__low2float(h), __high2float(h));
}

// ---------- 8-point DFT in registers, natural-order output ----------
template<bool INV>
__device__ inline void dft8(const float2 a[8], float2 X[8]) {
    const float C = 0.70710678118654752440f;
    float2 t0 = cadd(a[0], a[4]), t4 = csub(a[0], a[4]);
    float2 t1 = cadd(a[1], a[5]), d1 = csub(a[1], a[5]);
    float2 t2 = cadd(a[2], a[6]), d2 = csub(a[2], a[6]);
    float2 t3 = cadd(a[3], a[7]), d3 = csub(a[3], a[7]);
    float2 t5, t6, t7;
    if (!INV) {
        t5 = make_float2(C*(d1.x + d1.y), C*(d1.y - d1.x));
        t6 = make_float2(d2.y, -d2.x);
        t7 = make_float2(C*(d3.y - d3.x), -C*(d3.x + d3.y));
    } else {
        t5 = make_float2(C*(d1.x - d1.y), C*(d1.y + d1.x));
        t6 = make_float2(-d2.y, d2.x);
        t7 = make_float2(-C*(d3.x + d3.y), C*(d3.x - d3.y));
    }
    float2 u0 = cadd(t0, t2), u2 = csub(t0, t2);
    float2 u1 = cadd(t1, t3), e3 = csub(t1, t3);
    float2 u3 = INV ? make_float2(-e3.y, e3.x) : make_float2(e3.y, -e3.x);
    float2 u4 = cadd(t4, t6), u6 = csub(t4, t6);
    float2 u5 = cadd(t5, t7), e7 = csub(t5, t7);
    float2 u7 = INV ? make_float2(-e7.y, e7.x) : make_float2(e7.y, -e7.x);
    X[0] = cadd(u0, u1); X[4] = csub(u0, u1);
    X[2] = cadd(u2, u3); X[6] = csub(u2, u3);
    X[1] = cadd(u4, u5); X[5] = csub(u4, u5);
    X[3] = cadd(u6, u7); X[7] = csub(u6, u7);
}

// ---------- 512-pt FFT: radix-8^3, registers + 2 wave-private LDS exchanges ----
template<bool INV>
__device__ inline void fft512_reg(float2 a[8], float2* __restrict__ xch,
                                  int lane, float2 T1, float2 T2)
{
    float2 tw1 = INV ? make_float2(T1.x, -T1.y) : T1;
    float2 tw2 = INV ? make_float2(T2.x, -T2.y) : T2;
    const int rdo = lane + (lane >> 3);
    float2 b[8];

    dft8<INV>(a, b);
    { float2 w = tw1;
      #pragma unroll
      for (int k = 1; k < 8; ++k) { b[k] = cmulf(b[k], w); w = cmulf(w, tw1); } }
    #pragma unroll
    for (int k = 0; k < 8; ++k) xch[9*lane + k] = b[k];
    __asm__ volatile("s_waitcnt lgkmcnt(0)" ::: "memory");
    #pragma unroll
    for (int j = 0; j < 8; ++j) a[j] = xch[rdo + 72*j];

    dft8<INV>(a, b);
    { float2 w = tw2;
      #pragma unroll
      for (int k = 1; k < 8; ++k) { b[k] = cmulf(b[k], w); w = cmulf(w, tw2); } }
    { const int wbase = (lane & 7) + 72 * (lane >> 3);
      #pragma unroll
      for (int k = 0; k < 8; ++k) xch[wbase + 9*k] = b[k]; }
    __asm__ volatile("s_waitcnt lgkmcnt(0)" ::: "memory");
    #pragma unroll
    for (int j = 0; j < 8; ++j) b[j] = xch[rdo + 72*j];

    dft8<INV>(b, a);
}

// ---------- constants: propT/greenT/MT in TRANSPOSED [w][h] layout ----------
__global__ __launch_bounds__(256)
void k_pre(const float* __restrict__ kz, const float* __restrict__ otfa,
           const float* __restrict__ gmask, const float* __restrict__ otfp,
           float2* __restrict__ propT, float2* __restrict__ greenT,
           float2* __restrict__ MT)
{
    __shared__ float2 tp[32*33], tg[32*33], tm[32*33];
    const int tid = threadIdx.x;
    const int w0 = (blockIdx.x & 15) << 5;
    const int h0 = (blockIdx.x >> 4) << 5;
    const int ww = tid & 31, hh = tid >> 5;
    #pragma unroll
    for (int p = 0; p < 4; ++p) {
        int h = hh + p*8;
        int idx = (h0 + h)*512 + w0 + ww;
        float k = kz[idx];
        float sn, cs; __sincosf(k * 0.1f, &sn, &cs);
        float inv2 = 0.5f / k * gmask[idx];
        float phase = otfp[idx] - k * 0.5f;
        float s2, c2; __sincosf(phase, &s2, &c2);
        float oa = otfa[idx];
        tp[h*33 + ww] = make_float2(cs, sn);
        tg[h*33 + ww] = make_float2(-sn*inv2, cs*inv2);
        tm[h*33 + ww] = make_float2(oa*c2, oa*s2);
    }
    __syncthreads();
    #pragma unroll
    for (int p = 0; p < 4; ++p) {
        int wrow = hh + p*8;
        size_t o = (size_t)(w0 + wrow)*512 + h0 + ww;
        propT[o]  = tp[ww*33 + wrow];
        greenT[o] = tg[ww*33 + wrow];
        MT[o]     = tm[ww*33 + wrow];
    }
}

// ---------- sample [B,H,W,S] f32 -> sampT [S,B,H,W] bf16 complex (round-1 ver) --
__global__ __launch_bounds__(256)
void k_transpose(const float* __restrict__ sre, const float* __restrict__ sim,
                 ushort2* __restrict__ sampT)
{
    __shared__ ushort2 tile[40 * 129];
    const int bh = blockIdx.x;
    const int b = bh >> 9, h = bh & 511;
    const size_t src_base = (size_t)bh * (512 * 40);
    for (int chunk = 0; chunk < 4; ++chunk) {
        const int w0 = chunk * 128;
        __syncthreads();
        for (int j = threadIdx.x; j < 128 * 40; j += 256) {
            float re = sre[src_base + (size_t)w0 * 40 + j];
            float im = sim[src_base + (size_t)w0 * 40 + j];
            int w = j / 40;
            int s = j - w * 40;
            tile[s * 129 + w] = make_ushort2(f2bf(re), f2bf(im));
        }
        __syncthreads();
        for (int j = threadIdx.x; j < 128 * 40; j += 256) {
            int s = j >> 7, w = j & 127;
            sampT[(((size_t)s * 4 + b) * 512 + h) * 512 + w0 + w] = tile[s * 129 + w];
        }
    }
}

// ---------- persistent cooperative kernel: whole 40-slice loop ----------
// fldH: half2-packed field [b][h][w] (uint). inc/prop/green live in registers
// of the wave owning column (b,w). 82 grid syncs total.
__global__ __launch_bounds__(512)
void k_main(unsigned int* __restrict__ fldH,
            const float2* __restrict__ propT, const float2* __restrict__ greenT,
            const float2* __restrict__ MT,
            const ushort2* __restrict__ sampT,
            const float* __restrict__ pwre, const float* __restrict__ pwim,
            float* __restrict__ out)
{
    __shared__ float2 lds[8 * 576];            // xch regions; tile overlays
    unsigned int* tileu = (unsigned int*)lds;  // tile[h*9 + c], 4608 uints
    cg::grid_group grid = cg::this_grid();

    const int tid = threadIdx.x, lane = tid & 63, wv = tid >> 6;
    const int bk = blockIdx.x;
    float2* xch = &lds[wv * 576];

    float s1, c1, s2, c2;
    __sincosf(-6.2831853071795864769f * (float)lane / 512.0f, &s1, &c1);
    __sincosf(-6.2831853071795864769f * (float)(lane >> 3) / 64.0f, &s2, &c2);
    const float2 T1 = make_float2(c1, s1), T2 = make_float2(c2, s2);

    // row identity: r = bk*8 + wv  -> (rb, rh)
    const int r = bk * 8 + wv;
    const int rb = r >> 9, rh = r & 511;
    const size_t rbase = (size_t)r * 512;
    // col identity: block owns 8 columns w0..w0+7 of batch cb; wave -> w0+wv
    const int cb = bk >> 6;
    const int cw0 = (bk & 63) << 3;
    const size_t cbase = (size_t)cb * HW_ + cw0;      // fld tile base
    const size_t pbase = (size_t)(cw0 + wv) * 512;    // transposed const base
    const int cc = tid & 7, hb = tid >> 3;            // cooperative tile mapping

    float2 p[8], g[8], inc[8], a[8];
    #pragma unroll
    for (int k = 0; k < 8; ++k) {
        p[k] = propT[pbase + lane + (k << 6)];
        g[k] = greenT[pbase + lane + (k << 6)];
    }

    // R0: fld = Fr(planewave)
    #pragma unroll
    for (int j = 0; j < 8; ++j) {
        int w = lane + (j << 6);
        a[j] = make_float2(pwre[rbase + w], pwim[rbase + w]);
    }
    fft512_reg<false>(a, xch, lane, T1, T2);
    #pragma unroll
    for (int j = 0; j < 8; ++j) fldH[rbase + lane + (j << 6)] = pack_h2(a[j]);
    grid.sync();

    // C0: inc = Fc(fld)  (registers only)
    #pragma unroll
    for (int j = 0; j < 8; ++j) {
        int h = hb + (j << 6);
        tileu[h*9 + cc] = fldH[cbase + (size_t)h * 512 + cc];
    }
    __syncthreads();
    #pragma unroll
    for (int j = 0; j < 8; ++j) a[j] = unpack_h2(tileu[(lane + (j << 6))*9 + wv]);
    __syncthreads();
    fft512_reg<false>(a, xch, lane, T1, T2);
    #pragma unroll
    for (int k = 0; k < 8; ++k) inc[k] = a[k];
    grid.sync();

    for (int s = 0; s < 40; ++s) {
        // ---- row phase: fld = Fr( Br(fld) * samp * DZ/512 ) ----
        const size_t sbase = (size_t)s * 4 * HW_ + rbase;
        unsigned int su[8];
        #pragma unroll
        for (int j = 0; j < 8; ++j)
            su[j] = *(const unsigned int*)&sampT[sbase + lane + (j << 6)];
        #pragma unroll
        for (int j = 0; j < 8; ++j) a[j] = unpack_h2(fldH[rbase + lane + (j << 6)]);
        fft512_reg<true>(a, xch, lane, T1, T2);
        const float scale = 0.1f / 512.0f;
        #pragma unroll
        for (int j = 0; j < 8; ++j) {
            float sr = bf2f((unsigned short)(su[j] & 0xffffu));
            float si = bf2f((unsigned short)(su[j] >> 16));
            float2 v = a[j];
            a[j] = make_float2((v.x*sr - v.y*si) * scale, (v.x*si + v.y*sr) * scale);
        }
        fft512_reg<false>(a, xch, lane, T1, T2);
        #pragma unroll
        for (int j = 0; j < 8; ++j) fldH[rbase + lane + (j << 6)] = pack_h2(a[j]);
        grid.sync();

        // ---- col phase: s5=Fc(fld); nw=p*inc+g*s5 (+M); inc=nw; fld=Bc(nw)/512 --
        #pragma unroll
        for (int j = 0; j < 8; ++j) {
            int h = hb + (j << 6);
            tileu[h*9 + cc] = fldH[cbase + (size_t)h * 512 + cc];
        }
        __syncthreads();
        #pragma unroll
        for (int j = 0; j < 8; ++j) a[j] = unpack_h2(tileu[(lane + (j << 6))*9 + wv]);
        __syncthreads();
        fft512_reg<false>(a, xch, lane, T1, T2);   // s5
        #pragma unroll
        for (int k = 0; k < 8; ++k) {
            float2 s5 = a[k], io = inc[k];
            float2 nw = make_float2(
                p[k].x*io.x - p[k].y*io.y + g[k].x*s5.x - g[k].y*s5.y,
                p[k].x*io.y + p[k].y*io.x + g[k].x*s5.y + g[k].y*s5.x);
            if (s == 39) nw = cmulf(nw, MT[pbase + lane + (k << 6)]);
            inc[k] = nw;
            a[k] = nw;
        }
        fft512_reg<true>(a, xch, lane, T1, T2);    // Bc unnormalized
        __syncthreads();                            // all waves done with xch
        const float inv = 1.0f / 512.0f;
        #pragma unroll
        for (int k = 0; k < 8; ++k)
            tileu[(lane + (k << 6))*9 + wv] = pack_h2(make_float2(a[k].x*inv, a[k].y*inv));
        __syncthreads();
        #pragma unroll
        for (int j = 0; j < 8; ++j) {
            int h = hb + (j << 6);
            fldH[cbase + (size_t)h * 512 + cc] = tileu[h*9 + cc];
        }
        grid.sync();
    }

    // final row phase: out = |Br(fld)|/512, cropped to [32,480)^2
    #pragma unroll
    for (int j = 0; j < 8; ++j) a[j] = unpack_h2(fldH[rbase + lane + (j << 6)]);
    fft512_reg<true>(a, xch, lane, T1, T2);
    if (rh >= 32 && rh < 480) {
        float* orow = out + ((size_t)rb * 448 + (rh - 32)) * 448;
        #pragma unroll
        for (int j = 0; j < 8; ++j) {
            int w = lane + (j << 6);
            if (w >= 32 && w < 480) {
                float2 v = a[j];
                orow[w - 32] = sqrtf(v.x*v.x + v.y*v.y) * (1.0f / 512.0f);
            }
        }
    }
}

extern "C" void kernel_launch(void* const* d_in, const int* in_sizes, int n_in,
                              void* d_out, int out_size, void* d_ws, size_t ws_size,
                              hipStream_t stream)
{
    (void)in_sizes; (void)n_in; (void)out_size; (void)ws_size;
    const float* sre   = (const float*)d_in[0];
    const float* simg  = (const float*)d_in[1];
    const float* pwre  = (const float*)d_in[2];
    const float* pwim  = (const float*)d_in[3];
    const float* kz    = (const float*)d_in[4];
    const float* otfa  = (const float*)d_in[5];
    const float* gmask = (const float*)d_in[6];
    const float* otfp  = (const float*)d_in[7];

    char* ws = (char*)d_ws;
    size_t off = 0;
    float2* propT  = (float2*)(ws + off); off += (size_t)HW_ * 8;
    float2* greenT = (float2*)(ws + off); off += (size_t)HW_ * 8;
    float2* MT     = (float2*)(ws + off); off += (size_t)HW_ * 8;
    unsigned int* fldH = (unsigned int*)(ws + off); off += (size_t)4 * HW_ * 4;
    ushort2* sampT = (ushort2*)(ws + off);

    k_pre<<<256, 256, 0, stream>>>(kz, otfa, gmask, otfp, propT, greenT, MT);
    k_transpose<<<2048, 256, 0, stream>>>(sre, simg, sampT);

    float* outp = (float*)d_out;
    void* args[] = { (void*)&fldH, (void*)&propT, (void*)&greenT, (void*)&MT,
                     (void*)&sampT, (void*)&pwre, (void*)&pwim, (void*)&outp };
    hipLaunchCooperativeKernel((const void*)k_main, dim3(256), dim3(512),
                               args, 0, stream);
}